// Round 6
// baseline (80.111 us; speedup 1.0000x reference)
//
#include <hip/hip_runtime.h>
#include <hip/hip_bf16.h>
#include <stdint.h>

// Problem constants: B=4, N=4096, C=1024, H=16, d=64
typedef __attribute__((ext_vector_type(8))) short bf16x8;
typedef __attribute__((ext_vector_type(4))) short bf16x4;
typedef __attribute__((ext_vector_type(4))) float f32x4;
typedef __attribute__((ext_vector_type(4))) int   i32x4;

static __device__ __forceinline__ short f2bs(float f) {
  __hip_bfloat16 h = __float2bfloat16(f);
  return __builtin_bit_cast(short, h);
}

__device__ __forceinline__ void gload_lds16(const void* g, void* l) {
  auto* gp = reinterpret_cast<__attribute__((address_space(1))) uint32_t*>((uintptr_t)g);
  auto* lp = reinterpret_cast<__attribute__((address_space(3))) uint32_t*>((uintptr_t)l);
  __builtin_amdgcn_global_load_lds(gp, lp, 16, 0, 0);
}

// ---------------------------------------------------------------------------
// Kernel 1: per-token head-mix attention, fully in registers via MFMA.
// (unchanged — at ~87% of its memory floor in the timed run)
// ---------------------------------------------------------------------------
__global__ __launch_bounds__(256) void attn_kernel(
    const float* __restrict__ x, const float* __restrict__ y,
    __hip_bfloat16* __restrict__ A)
{
  const int wid  = threadIdx.x >> 6;
  const int lane = threadIdx.x & 63;
  const int tok  = blockIdx.x * 4 + wid;        // 0..16383
  const int b    = tok >> 12;
  const int n    = tok & 4095;

  const float* xr = x + (size_t)tok * 1024;
  const float* yr = y + (size_t)tok * 1024;

  const int c  = lane & 15;
  const int qq = lane >> 4;

  const int fbase = c * 64 + qq * 8;
  bf16x8 yf[2], xf[2];
  #pragma unroll
  for (int kk = 0; kk < 2; ++kk) {
    const float4 a0 = *(const float4*)(yr + fbase + kk * 32);
    const float4 a1 = *(const float4*)(yr + fbase + kk * 32 + 4);
    const float4 b0 = *(const float4*)(xr + fbase + kk * 32);
    const float4 b1 = *(const float4*)(xr + fbase + kk * 32 + 4);
    yf[kk] = bf16x8{f2bs(a0.x), f2bs(a0.y), f2bs(a0.z), f2bs(a0.w),
                    f2bs(a1.x), f2bs(a1.y), f2bs(a1.z), f2bs(a1.w)};
    xf[kk] = bf16x8{f2bs(b0.x), f2bs(b0.y), f2bs(b0.z), f2bs(b0.w),
                    f2bs(b1.x), f2bs(b1.y), f2bs(b1.z), f2bs(b1.w)};
  }

  f32x4 acc = {0.f, 0.f, 0.f, 0.f};
  acc = __builtin_amdgcn_mfma_f32_16x16x32_bf16(yf[0], xf[0], acc, 0, 0, 0);
  acc = __builtin_amdgcn_mfma_f32_16x16x32_bf16(yf[1], xf[1], acc, 0, 0, 0);

  float sc[4];
  #pragma unroll
  for (int r = 0; r < 4; ++r) sc[r] = acc[r] * 0.125f;
  float mx = fmaxf(fmaxf(sc[0], sc[1]), fmaxf(sc[2], sc[3]));
  mx = fmaxf(mx, __shfl_xor(mx, 16));
  mx = fmaxf(mx, __shfl_xor(mx, 32));
  float e[4];
  #pragma unroll
  for (int r = 0; r < 4; ++r) e[r] = __expf(sc[r] - mx);
  float sm = (e[0] + e[1]) + (e[2] + e[3]);
  sm += __shfl_xor(sm, 16);
  sm += __shfl_xor(sm, 32);
  const float inv = 1.0f / sm;
  float p[4];
  #pragma unroll
  for (int r = 0; r < 4; ++r) p[r] = e[r] * inv;

  f32x4 o[4];
  #pragma unroll
  for (int q = 0; q < 4; ++q) o[q] = f32x4{0.f, 0.f, 0.f, 0.f};

#if __has_builtin(__builtin_amdgcn_mfma_f32_16x16x16bf16_1k)
  const bf16x4 pa = {f2bs(p[0]), f2bs(p[1]), f2bs(p[2]), f2bs(p[3])};
  #pragma unroll
  for (int q = 0; q < 4; ++q) {
    bf16x4 bq;
    #pragma unroll
    for (int j = 0; j < 4; ++j)
      bq[j] = f2bs(yr[(qq * 4 + j) * 64 + q * 16 + c]);
    o[q] = __builtin_amdgcn_mfma_f32_16x16x16bf16_1k(pa, bq, o[q], 0, 0, 0);
  }
#else
  const int u0 = ((int)(unsigned short)f2bs(p[1]) << 16) | (unsigned short)f2bs(p[0]);
  const int u1 = ((int)(unsigned short)f2bs(p[3]) << 16) | (unsigned short)f2bs(p[2]);
  const int s0 = c + 32 * qq;
  int a0 = __shfl(u0, s0), a1 = __shfl(u1, s0);
  int a2 = __shfl(u0, s0 + 16), a3 = __shfl(u1, s0 + 16);
  const bool valid = (qq < 2);
  if (!valid) { a0 = 0; a1 = 0; a2 = 0; a3 = 0; }
  const bf16x8 a8 = __builtin_bit_cast(bf16x8, i32x4{a0, a1, a2, a3});
  #pragma unroll
  for (int q = 0; q < 4; ++q) {
    bf16x8 b8;
    #pragma unroll
    for (int j = 0; j < 8; ++j) {
      const int g = (qq * 8 + j) & 15;
      const float v = yr[g * 64 + q * 16 + c];
      b8[j] = valid ? f2bs(v) : (short)0;
    }
    o[q] = __builtin_amdgcn_mfma_f32_16x16x32_bf16(a8, b8, o[q], 0, 0, 0);
  }
#endif

  const size_t base = ((size_t)b * 4096 + (n >> 4)) * 1024 + ((n & 15) << 6) + c;
  #pragma unroll
  for (int q = 0; q < 4; ++q)
    #pragma unroll
    for (int r = 0; r < 4; ++r) {
      const int h = qq * 4 + r;
      A[base + (size_t)h * 262144 + q * 16] = __float2bfloat16(o[q][r]);
    }
}

// ---------------------------------------------------------------------------
// Kernel 2: W fp32 -> bf16
// ---------------------------------------------------------------------------
__global__ __launch_bounds__(256) void wcvt_kernel(const float* __restrict__ w,
                                                   __hip_bfloat16* __restrict__ wb)
{
  const int i = (blockIdx.x * 256 + threadIdx.x) * 4;
  const float4 v = *(const float4*)(w + i);
  wb[i + 0] = __float2bfloat16(v.x);
  wb[i + 1] = __float2bfloat16(v.y);
  wb[i + 2] = __float2bfloat16(v.z);
  wb[i + 3] = __float2bfloat16(v.w);
}

// ---------------------------------------------------------------------------
// Kernel 3: out[M,Nn] = A[M,K] * Bw[Nn,K]^T + bias, fp32 out.
// 128x128 tile, BK=32, 4 waves (wave-tile 64x64, acc[4][4]), TRIPLE-buffered
// LDS (3 x 16 KB), depth-2 prefetch, ONE barrier per K-tile, counted vmcnt
// (gate to 4, never drain until tail). 3 blocks/CU (LDS-capped). Swizzle for
// 64B rows: slot ^= (row>>1)&3  -> worst-case 2-way (free). XCD-chunked grid.
// ---------------------------------------------------------------------------
#define NT 32   // K / 32

#define FENCE asm volatile("" ::: "memory")
#define BAR   __builtin_amdgcn_s_barrier()
#define LGKM0 asm volatile("s_waitcnt lgkmcnt(0)" ::: "memory")
#define VM4   asm volatile("s_waitcnt vmcnt(4)" ::: "memory")
#define VM0   asm volatile("s_waitcnt vmcnt(0)" ::: "memory")
#define SB0   __builtin_amdgcn_sched_barrier(0)
#define SP1   __builtin_amdgcn_s_setprio(1)
#define SP0   __builtin_amdgcn_s_setprio(0)

// One K-tile of staging: A 8KB (2 issues x 64 rows) + B 8KB. toff/bo in bytes.
#define STAGE(toff, bo) do {                                        \
    gload_lds16(aSrc + (toff),          aDst + (bo));               \
    gload_lds16(aSrc + (toff) + 131072, aDst + (bo) + 4096);        \
    gload_lds16(bSrc + (toff),          bDst + (bo));               \
    gload_lds16(bSrc + (toff) + 131072, bDst + (bo) + 4096);        \
  } while (0)

__global__ __launch_bounds__(256, 3) void gemm128(
    const __hip_bfloat16* __restrict__ A,   // [M,K] row-major bf16
    const __hip_bfloat16* __restrict__ Bw,  // [Nn,K] row-major bf16 (= W^T)
    const float* __restrict__ bias,         // [Nn]
    float* __restrict__ C)                  // [M,Nn] fp32
{
  constexpr int K = 1024, Nn = 1024;
  __shared__ char ldsA[3 * 8192];           // [buf][128 rows][64B], swizzled
  __shared__ char ldsB[3 * 8192];

  const int tid  = threadIdx.x;             // 0..255
  const int lane = tid & 63;
  const int wid  = tid >> 6;                // 4 waves, 2M x 2N
  const int wr   = wid >> 1;                // 0..1 (M half: 64 rows)
  const int wcN  = wid & 1;                 // 0..1 (N half: 64 cols)

  // XCD-chunked bijective swizzle: 1024 blocks = 8 XCDs x 128 tiles.
  // Within an XCD chunk nt varies fastest -> A-panel reused 8x from L2.
  const int bid = blockIdx.x;
  const int nb  = (bid & 7) * 128 + (bid >> 3);
  const int mBase = (nb >> 3) * 128;        // 128 M-tiles
  const int nBase = (nb & 7) * 128;         // 8 N-tiles

  // ---- staging: linear LDS dest, pre-swizzled global source ----
  // issue covers 64 rows: thread t -> row t>>2, phys slot t&3 (16B slots)
  // swizzle involution: slot ^= (row>>1)&3
  const int srow = tid >> 2;
  const int lcb  = (((tid & 3) ^ ((tid >> 3) & 3)) << 4);
  const char* aSrc = (const char*)A  + (size_t)(mBase + srow) * (K * 2) + lcb;
  const char* bSrc = (const char*)Bw + (size_t)(nBase + srow) * (K * 2) + lcb;
  char* aDst = ldsA + tid * 16;
  char* bDst = ldsB + tid * 16;

  // ---- ds_read geometry (swizzled): row R -> byte R*64 + (kq^((R>>1)&3))*16
  const int fr = lane & 15;                 // fragment row
  const int kq = lane >> 4;                 // k-quad
  const int ofk  = ((kq ^ ((fr >> 1) & 3)) << 4);
  const int aOff = (wr  * 64 + fr) * 64 + ofk;
  const int bOff = (wcN * 64 + fr) * 64 + ofk;

  f32x4 acc[4][4];
  #pragma unroll
  for (int m = 0; m < 4; ++m)
    #pragma unroll
    for (int n = 0; n < 4; ++n) acc[m][n] = f32x4{0.f, 0.f, 0.f, 0.f};

  // ---- prologue: stage tiles 0,1; ensure tile 0 landed ----
  STAGE(0, 0);
  STAGE(64, 8192);
  VM4; FENCE; BAR; FENCE;

  // ---- one K-tile: stage t+2, read buf b0, 16 MFMA, gate, barrier ----
  auto tile = [&](int t, int b0off, int b2off, int stg, int gate) {
    if (stg) STAGE((t + 2) * 64, b2off);
    bf16x8 Af[4], Bf[4];
    const char* aB = ldsA + b0off + aOff;
    const char* bB = ldsB + b0off + bOff;
    #pragma unroll
    for (int n = 0; n < 4; ++n) Bf[n] = *(const bf16x8*)(bB + n * 1024);
    #pragma unroll
    for (int m = 0; m < 4; ++m) Af[m] = *(const bf16x8*)(aB + m * 1024);
    LGKM0; SB0;
    SP1;
    #pragma unroll
    for (int m = 0; m < 4; ++m)
      #pragma unroll
      for (int n = 0; n < 4; ++n)
        acc[m][n] = __builtin_amdgcn_mfma_f32_16x16x32_bf16(Af[m], Bf[n], acc[m][n], 0, 0, 0);
    SP0;
    if (gate == 4) { VM4; }
    else if (gate == 0) { VM0; }
    FENCE; BAR; FENCE;
  };

  // main: tiles 0..29 in groups of 3 (static buffer indices), tail 30,31
  for (int t = 0; t < 30; t += 3) {
    tile(t,     0,     16384, 1, 4);
    tile(t + 1, 8192,  0,     1, 4);
    tile(t + 2, 16384, 8192,  1, 4);
  }
  tile(30, 0,    0, 0, 0);   // drain last 4 loads (tile 31's)
  tile(31, 8192, 0, 0, -1);  // nothing outstanding

  // ---- epilogue: C/D layout col=lane&15, row=(lane>>4)*4+reg ----
  // Overlapped by the other 2 resident blocks' K-loops.
  const int fq = lane >> 4;
  #pragma unroll
  for (int n = 0; n < 4; ++n) {
    const int col = nBase + wcN * 64 + n * 16 + fr;
    const float bv = bias[col];
    #pragma unroll
    for (int m = 0; m < 4; ++m) {
      const int row0 = mBase + wr * 64 + m * 16 + fq * 4;
      #pragma unroll
      for (int r = 0; r < 4; ++r)
        C[(size_t)(row0 + r) * Nn + col] = acc[m][n][r] + bv;
    }
  }
}

extern "C" void kernel_launch(void* const* d_in, const int* in_sizes, int n_in,
                              void* d_out, int out_size, void* d_ws, size_t ws_size,
                              hipStream_t stream) {
  const float* x    = (const float*)d_in[0];
  const float* y    = (const float*)d_in[1];
  const float* W    = (const float*)d_in[2];
  const float* bias = (const float*)d_in[3];
  float* out = (float*)d_out;

  // Workspace: A (16384x1024 bf16 = 32 MB) + Wbf16 (2 MB)
  __hip_bfloat16* Abuf = (__hip_bfloat16*)d_ws;
  __hip_bfloat16* Wbuf = (__hip_bfloat16*)((char*)d_ws + (size_t)16384 * 1024 * 2);

  wcvt_kernel<<<1024, 256, 0, stream>>>(W, Wbuf);
  attn_kernel<<<4096, 256, 0, stream>>>(x, y, Abuf);
  gemm128<<<1024, 256, 0, stream>>>(Abuf, Wbuf, bias, out);
}